// Round 4
// baseline (66.939 us; speedup 1.0000x reference)
//
#include <hip/hip_runtime.h>
#include <stdint.h>

#define DD 512
#define NP 1024
#define NB 16

typedef __attribute__((ext_vector_type(8))) __bf16 bf16x8;
typedef __attribute__((ext_vector_type(4))) float f32x4;

// ---------- kernel 0: build EHW bf16 table in MFMA-fragment order ----------
// EHW row r (r<32):  eh'[r]  = embed[r*32, :]          (embed flat [1024][512])
// EHW row r (r>=32): ew'[r-32] = embed[r-32, :] - embed[0, :]
// layout: ehwf[((ks*64 + row)*4 + c)*8 + e] = EHW[row][ks*32 + c*8 + e]
__global__ __launch_bounds__(256) void prep_ehwf(
    const float* __restrict__ embed, unsigned short* __restrict__ ehwf)
{
    int g = blockIdx.x * 256 + threadIdx.x;      // 0..4095
    int c = g & 3;
    int row = (g >> 2) & 63;
    int ks = g >> 8;
    int col = ks * 32 + c * 8;
    int srcrow = (row < 32) ? (row << 5) : (row - 32);
    const float* src = embed + (size_t)srcrow * DD + col;
    float4 a = *(const float4*)src;
    float4 d = *(const float4*)(src + 4);
    if (row >= 32) {
        float4 z0 = *(const float4*)(embed + col);
        float4 z1 = *(const float4*)(embed + col + 4);
        a.x -= z0.x; a.y -= z0.y; a.z -= z0.z; a.w -= z0.w;
        d.x -= z1.x; d.y -= z1.y; d.z -= z1.z; d.w -= z1.w;
    }
    bf16x8 r;
    r[0]=(__bf16)a.x; r[1]=(__bf16)a.y; r[2]=(__bf16)a.z; r[3]=(__bf16)a.w;
    r[4]=(__bf16)d.x; r[5]=(__bf16)d.y; r[6]=(__bf16)d.z; r[7]=(__bf16)d.w;
    *(bf16x8*)(ehwf + (size_t)g * 8) = r;
}

// ---------- kernel 1: rank-64 thin GEMMs, no LDS, no barriers ----------
// blocks 0..511   (G1): qhw[P][m]   = q[b,P,:]·EHW[m,:]   (P = global row)
// blocks 512..1023(G2): khw[b][m][Q] = EHW[m,:]·(k[b,Q,:]+E[Q,:])
// wave tile: 16 streamed rows x 32 EHW rows; block = 2x2 wave tiles.
__global__ __launch_bounds__(256, 4) void rank_gemm(
    const float* __restrict__ q, const float* __restrict__ kin,
    const float* __restrict__ embed,
    const unsigned short* __restrict__ ehwf,
    float* __restrict__ qhw, float* __restrict__ khw)
{
    const int tid  = threadIdx.x;
    const int lane = tid & 63;
    const int wid  = tid >> 6;
    const int wa = wid >> 1;          // streamed-row group (0/1)
    const int wn = wid & 1;           // EHW half (0/1)
    const int lr = lane & 15;
    const int kq = (lane >> 4) * 8;

    const bool g2 = blockIdx.x >= 512;
    const float* srcA;
    const float* srcE = nullptr;
    if (!g2) {
        srcA = q + (size_t)(blockIdx.x * 32 + wa * 16 + lr) * DD + kq;
    } else {
        int gi = blockIdx.x - 512;
        int b = gi >> 5, qt = gi & 31;
        int Q = qt * 32 + wa * 16 + lr;
        srcA = kin + ((size_t)b * NP + Q) * DD + kq;
        srcE = embed + (size_t)Q * DD + kq;
    }
    // table base for this lane: rows wn*32 (+16 for second frag)
    const unsigned short* tb =
        ehwf + ((size_t)(wn * 32 + lr) * 4 + (lane >> 4)) * 8;

    f32x4 acc0 = (f32x4)0.0f, acc1 = (f32x4)0.0f;

    #pragma unroll 4
    for (int ks = 0; ks < 16; ++ks) {
        float4 a0 = *(const float4*)(srcA + ks * 32);
        float4 a1 = *(const float4*)(srcA + ks * 32 + 4);
        if (g2) {
            float4 e0 = *(const float4*)(srcE + ks * 32);
            float4 e1 = *(const float4*)(srcE + ks * 32 + 4);
            a0.x += e0.x; a0.y += e0.y; a0.z += e0.z; a0.w += e0.w;
            a1.x += e1.x; a1.y += e1.y; a1.z += e1.z; a1.w += e1.w;
        }
        bf16x8 sf;
        sf[0]=(__bf16)a0.x; sf[1]=(__bf16)a0.y; sf[2]=(__bf16)a0.z; sf[3]=(__bf16)a0.w;
        sf[4]=(__bf16)a1.x; sf[5]=(__bf16)a1.y; sf[6]=(__bf16)a1.z; sf[7]=(__bf16)a1.w;
        bf16x8 ef0 = *(const bf16x8*)(tb + (size_t)ks * 2048);
        bf16x8 ef1 = *(const bf16x8*)(tb + (size_t)ks * 2048 + 512);
        if (!g2) {
            acc0 = __builtin_amdgcn_mfma_f32_16x16x32_bf16(sf, ef0, acc0, 0, 0, 0);
            acc1 = __builtin_amdgcn_mfma_f32_16x16x32_bf16(sf, ef1, acc1, 0, 0, 0);
        } else {
            acc0 = __builtin_amdgcn_mfma_f32_16x16x32_bf16(ef0, sf, acc0, 0, 0, 0);
            acc1 = __builtin_amdgcn_mfma_f32_16x16x32_bf16(ef1, sf, acc1, 0, 0, 0);
        }
    }

    // C/D: col = lane&15 (B row), row = (lane>>4)*4 + i (A row)
    if (!g2) {
        // C row -> P (streamed), C col -> EHW row m
        float* o = qhw + (size_t)(blockIdx.x * 32 + wa * 16 + (lane >> 4) * 4) * 64
                       + wn * 32 + lr;
        #pragma unroll
        for (int i = 0; i < 4; ++i) o[(size_t)i * 64]      = acc0[i];
        #pragma unroll
        for (int i = 0; i < 4; ++i) o[(size_t)i * 64 + 16] = acc1[i];
    } else {
        int gi = blockIdx.x - 512;
        int b = gi >> 5, qt = gi & 31;
        int Q = qt * 32 + wa * 16 + lr;           // C col -> Q (streamed B)
        float* o = khw + (size_t)b * 64 * NP + Q;
        int m0 = wn * 32 + (lane >> 4) * 4;       // C row -> EHW row m
        #pragma unroll
        for (int i = 0; i < 4; ++i) o[(size_t)(m0 + i) * NP]      = acc0[i];
        #pragma unroll
        for (int i = 0; i < 4; ++i) o[(size_t)(m0 + 16 + i) * NP] = acc1[i];
    }
}

// ---------- kernel 2: broadcast assembly (write-BW bound) ----------
// out[b][P=(i,j)][Q=(k,l)] = qhw[b,P][k] + qhw[b,P][32+l]
//                          + khw[b][i][Q] + khw[b][32+j][Q]
__global__ __launch_bounds__(256) void assemble(
    const float* __restrict__ qhw, const float* __restrict__ khw,
    float* __restrict__ out)
{
    __shared__ __align__(16) float kh[NP];
    __shared__ __align__(16) float qq[16 * 64];

    const int tid = threadIdx.x;
    const int b   = blockIdx.x >> 6;
    const int i   = (blockIdx.x >> 1) & 31;
    const int jh  = blockIdx.x & 1;

    ((float4*)kh)[tid] = ((const float4*)(khw + ((size_t)b * 64 + i) * NP))[tid];
    ((float4*)qq)[tid] =
        ((const float4*)(qhw + ((size_t)(b * NP + i * 32 + jh * 16)) * 64))[tid];
    __syncthreads();

    const int Q0 = tid * 4;
    const int kidx = Q0 >> 5;
    const int lidx = Q0 & 31;
    const float4 khv = *(const float4*)&kh[Q0];

    float* orow = out + ((size_t)(b * NP + i * 32 + jh * 16)) * NP + Q0;
    const float* kwbase = khw + ((size_t)b * 64 + 32 + jh * 16) * NP + Q0;

    #pragma unroll 4
    for (int jj = 0; jj < 16; ++jj) {
        float4 kw = *(const float4*)(kwbase + (size_t)jj * NP);
        float qh  = qq[jj * 64 + kidx];
        float4 qw = *(const float4*)&qq[jj * 64 + 32 + lidx];
        float4 v;
        v.x = khv.x + kw.x + qh + qw.x;
        v.y = khv.y + kw.y + qh + qw.y;
        v.z = khv.z + kw.z + qh + qw.z;
        v.w = khv.w + kw.w + qh + qw.w;
        *(float4*)(orow + (size_t)jj * NP) = v;
    }
}

extern "C" void kernel_launch(void* const* d_in, const int* in_sizes, int n_in,
                              void* d_out, int out_size, void* d_ws, size_t ws_size,
                              hipStream_t stream) {
    const float* q = (const float*)d_in[0];
    const float* k = (const float*)d_in[1];
    const float* e = (const float*)d_in[2];
    float* out = (float*)d_out;

    float* qhw = (float*)d_ws;                         // [16384][64]    4 MB
    float* khw = qhw + (size_t)NB * NP * 64;           // [16][64][1024] 4 MB
    unsigned short* ehwf = (unsigned short*)(khw + (size_t)NB * 64 * NP); // 64 KB

    hipLaunchKernelGGL(prep_ehwf, dim3(16), dim3(256), 0, stream, e, ehwf);
    hipLaunchKernelGGL(rank_gemm, dim3(1024), dim3(256), 0, stream,
                       q, k, e, ehwf, qhw, khw);
    hipLaunchKernelGGL(assemble, dim3(1024), dim3(256), 0, stream, qhw, khw, out);
}